// Round 1
// baseline (555.577 us; speedup 1.0000x reference)
//
#include <hip/hip_runtime.h>
#include <math.h>

#define BB 16
#define CC 64
#define HH 256
#define WW 256
#define HWSZ (HH * WW)
#define NP (BB * CC)   // 1024 planes
#define BAND 64        // rows per block in conv kernel

// ---------------- Kernel 1: per-plane mean ----------------
__global__ __launch_bounds__(256) void mean_kernel(const float* __restrict__ x,
                                                   float* __restrict__ avg) {
    int p = blockIdx.x;
    const float4* xp = (const float4*)(x + (size_t)p * HWSZ);
    float s = 0.f;
    for (int i = threadIdx.x; i < HWSZ / 4; i += 256) {
        float4 v = xp[i];
        s += v.x + v.y + v.z + v.w;
    }
    // wave (64-lane) reduction
    for (int off = 32; off > 0; off >>= 1) s += __shfl_down(s, off, 64);
    __shared__ float ws[4];
    int lane = threadIdx.x & 63, wid = threadIdx.x >> 6;
    if (lane == 0) ws[wid] = s;
    __syncthreads();
    if (threadIdx.x == 0) {
        avg[p] = (ws[0] + ws[1] + ws[2] + ws[3]) * (1.0f / (float)HWSZ);
    }
}

// ---------------- Kernel 2: dyn = avg @ w1.T + b1, sigmoid ----------------
// dyn[b, j] = sum_c avg[b,c] * w1[j,c] + b1[j],  j in [0, 576)
// wk flat index b*576 + j == plane(b*64 + j/9)*9 + (j%9)  -- matches reshape.
__global__ __launch_bounds__(256) void wk_kernel(const float* __restrict__ avg,
                                                 const float* __restrict__ w1,
                                                 const float* __restrict__ b1,
                                                 float* __restrict__ wk) {
    int idx = blockIdx.x * 256 + threadIdx.x;
    if (idx >= BB * CC * 9) return;
    int b = idx / (CC * 9);
    int j = idx % (CC * 9);
    const float* a = avg + b * CC;
    const float* wrow = w1 + (size_t)j * CC;
    float s = b1[j];
#pragma unroll
    for (int c2 = 0; c2 < CC; ++c2) s += a[c2] * wrow[c2];
    wk[idx] = 1.0f / (1.0f + expf(-s));
}

// ---------------- Kernel 3: depthwise 3x3 conv + fused epilogue ----------------
// grid = (H/BAND, NP), block = 256. Rolling 4-row LDS buffer, 1 sync/row.
__global__ __launch_bounds__(256) void conv_kernel(const float* __restrict__ x,
                                                   const float* __restrict__ wk,
                                                   const float* __restrict__ fscale,
                                                   const float* __restrict__ conv_bias,
                                                   float* __restrict__ out) {
    const int p = blockIdx.y;          // plane 0..1023
    const int band = blockIdx.x;       // 0..3
    const int c = p & (CC - 1);
    const int h0 = band * BAND;
    const float* xp = x + (size_t)p * HWSZ;
    float* op = out + (size_t)p * HWSZ;

    __shared__ float lds[4][WW + 4];   // index = w+1; [0] and [WW+1] are zero halo
    __shared__ float wsh[9];

    if (threadIdx.x < 9) wsh[threadIdx.x] = wk[p * 9 + threadIdx.x];
    if (threadIdx.x < 4) {
        lds[threadIdx.x][0] = 0.f;
        lds[threadIdx.x][WW + 1] = 0.f;
    }
    const float fs = fscale[c];
    const float cb = conv_bias[c];

    auto load_row = [&](int r) {
        if (threadIdx.x < 64) {
            float4 v;
            if (r >= 0 && r < HH) v = ((const float4*)(xp + r * WW))[threadIdx.x];
            else                  v = make_float4(0.f, 0.f, 0.f, 0.f);
            float* dst = &lds[(r + 4) & 3][1 + threadIdx.x * 4];
            dst[0] = v.x; dst[1] = v.y; dst[2] = v.z; dst[3] = v.w;
        }
    };

    load_row(h0 - 1);
    load_row(h0);
    __syncthreads();

    for (int h = h0; h < h0 + BAND; ++h) {
        load_row(h + 1);
        __syncthreads();
        // 4-buffer rolling scheme: the buffer written next iteration,
        // (h+2)&3, is never one of the three read here -> no trailing sync.
        const int t = threadIdx.x;
        const float* r0 = lds[(h - 1 + 4) & 3];
        const float* r1 = lds[(h + 4) & 3];
        const float* r2 = lds[(h + 1 + 4) & 3];
        float y = cb;
        y += wsh[0] * r0[t] + wsh[1] * r0[t + 1] + wsh[2] * r0[t + 2];
        y += wsh[3] * r1[t] + wsh[4] * r1[t + 1] + wsh[5] * r1[t + 2];
        y += wsh[6] * r2[t] + wsh[7] * r2[t + 1] + wsh[8] * r2[t + 2];
        const float xv = r1[t + 1];
        op[h * WW + t] = (xv - y) * fs * xv + y;
    }
}

extern "C" void kernel_launch(void* const* d_in, const int* in_sizes, int n_in,
                              void* d_out, int out_size, void* d_ws, size_t ws_size,
                              hipStream_t stream) {
    const float* x         = (const float*)d_in[0];
    const float* w1        = (const float*)d_in[1];
    const float* b1        = (const float*)d_in[2];
    const float* fscale    = (const float*)d_in[3];
    const float* conv_bias = (const float*)d_in[4];
    float* out = (float*)d_out;

    float* avg = (float*)d_ws;        // 1024 floats
    float* wk  = avg + NP;            // 9216 floats

    mean_kernel<<<NP, 256, 0, stream>>>(x, avg);
    wk_kernel<<<(BB * CC * 9 + 255) / 256, 256, 0, stream>>>(avg, w1, b1, wk);
    dim3 grid(HH / BAND, NP);
    conv_kernel<<<grid, 256, 0, stream>>>(x, wk, fscale, conv_bias, out);
}

// Round 2
// 509.153 us; speedup vs baseline: 1.0912x; 1.0912x over previous
//
#include <hip/hip_runtime.h>
#include <math.h>

#define BB 16
#define CC 64
#define HH 256
#define WW 256
#define HWSZ (HH * WW)
#define NP (BB * CC)   // 1024 planes

// ---------------- Kernel 1: per-plane mean ----------------
__global__ __launch_bounds__(256) void mean_kernel(const float* __restrict__ x,
                                                   float* __restrict__ avg) {
    int p = blockIdx.x;
    const float4* xp = (const float4*)(x + (size_t)p * HWSZ);
    float s0 = 0.f, s1 = 0.f, s2 = 0.f, s3 = 0.f;
    for (int i = threadIdx.x; i < HWSZ / 4; i += 1024) {
        float4 a = xp[i];
        float4 b = xp[i + 256];
        float4 c = xp[i + 512];
        float4 d = xp[i + 768];
        s0 += a.x + a.y + a.z + a.w;
        s1 += b.x + b.y + b.z + b.w;
        s2 += c.x + c.y + c.z + c.w;
        s3 += d.x + d.y + d.z + d.w;
    }
    float s = (s0 + s1) + (s2 + s3);
    for (int off = 32; off > 0; off >>= 1) s += __shfl_down(s, off, 64);
    __shared__ float ws[4];
    int lane = threadIdx.x & 63, wid = threadIdx.x >> 6;
    if (lane == 0) ws[wid] = s;
    __syncthreads();
    if (threadIdx.x == 0) {
        avg[p] = (ws[0] + ws[1] + ws[2] + ws[3]) * (1.0f / (float)HWSZ);
    }
}

// ---------------- Kernel 2: dyn = avg @ w1.T + b1, sigmoid ----------------
__global__ __launch_bounds__(256) void wk_kernel(const float* __restrict__ avg,
                                                 const float* __restrict__ w1,
                                                 const float* __restrict__ b1,
                                                 float* __restrict__ wk) {
    int idx = blockIdx.x * 256 + threadIdx.x;
    if (idx >= BB * CC * 9) return;
    int b = idx / (CC * 9);
    int j = idx % (CC * 9);
    const float* a = avg + b * CC;
    const float* wrow = w1 + (size_t)j * CC;
    float s = b1[j];
#pragma unroll
    for (int c2 = 0; c2 < CC; ++c2) s += a[c2] * wrow[c2];
    wk[idx] = 1.0f / (1.0f + expf(-s));
}

// ---------------- Kernel 3: depthwise 3x3 conv + fused epilogue ----------------
// Barrier-free register streaming. grid = NP blocks of 256 threads (4 waves).
// Wave w owns rows [w*64, w*64+64) of plane blockIdx.x. Lane j owns cols
// [4j, 4j+3] (float4 loads/stores, 16 B/lane). Horizontal halo via shuffles,
// vertical via a 3-row register window with 1-row prefetch.
__global__ __launch_bounds__(256) void conv_kernel(const float* __restrict__ x,
                                                   const float* __restrict__ wk,
                                                   const float* __restrict__ fscale,
                                                   const float* __restrict__ conv_bias,
                                                   float* __restrict__ out) {
    const int p = blockIdx.x;
    const int wave = threadIdx.x >> 6;
    const int lane = threadIdx.x & 63;
    const int c = p & (CC - 1);
    const int h0 = wave * (HH / 4);
    const float* xp = x + (size_t)p * HWSZ;
    float* op = out + (size_t)p * HWSZ;

    float k0 = wk[p * 9 + 0], k1 = wk[p * 9 + 1], k2 = wk[p * 9 + 2];
    float k3 = wk[p * 9 + 3], k4 = wk[p * 9 + 4], k5 = wk[p * 9 + 5];
    float k6 = wk[p * 9 + 6], k7 = wk[p * 9 + 7], k8 = wk[p * 9 + 8];
    const float fs = fscale[c];
    const float cb = conv_bias[c];

    auto ldrow = [&](int r) -> float4 {
        if ((unsigned)r < (unsigned)HH) return ((const float4*)(xp + r * WW))[lane];
        return make_float4(0.f, 0.f, 0.f, 0.f);
    };
    auto haloL = [&](float w) { float v = __shfl_up(w, 1, 64); return lane == 0 ? 0.f : v; };
    auto haloR = [&](float v0) { float v = __shfl_down(v0, 1, 64); return lane == 63 ? 0.f : v; };

    float4 rp = ldrow(h0 - 1);   // row h-1
    float4 rc = ldrow(h0);       // row h
    float4 rn = ldrow(h0 + 1);   // row h+1
    float lp = haloL(rp.w), Rp = haloR(rp.x);
    float lc = haloL(rc.w), Rc = haloR(rc.x);

    for (int h = h0; h < h0 + HH / 4; ++h) {
        float4 rn2 = ldrow(h + 2);           // prefetch: not needed this iter
        float ln = haloL(rn.w), Rn = haloR(rn.x);

        float4 y;
        y.x = cb + k0 * lp   + k1 * rp.x + k2 * rp.y
                 + k3 * lc   + k4 * rc.x + k5 * rc.y
                 + k6 * ln   + k7 * rn.x + k8 * rn.y;
        y.y = cb + k0 * rp.x + k1 * rp.y + k2 * rp.z
                 + k3 * rc.x + k4 * rc.y + k5 * rc.z
                 + k6 * rn.x + k7 * rn.y + k8 * rn.z;
        y.z = cb + k0 * rp.y + k1 * rp.z + k2 * rp.w
                 + k3 * rc.y + k4 * rc.z + k5 * rc.w
                 + k6 * rn.y + k7 * rn.z + k8 * rn.w;
        y.w = cb + k0 * rp.z + k1 * rp.w + k2 * Rp
                 + k3 * rc.z + k4 * rc.w + k5 * Rc
                 + k6 * rn.z + k7 * rn.w + k8 * Rn;

        float4 o;
        o.x = (rc.x - y.x) * fs * rc.x + y.x;
        o.y = (rc.y - y.y) * fs * rc.y + y.y;
        o.z = (rc.z - y.z) * fs * rc.z + y.z;
        o.w = (rc.w - y.w) * fs * rc.w + y.w;
        ((float4*)(op + h * WW))[lane] = o;

        rp = rc; rc = rn; rn = rn2;
        lp = lc; Rp = Rc;
        lc = ln; Rc = Rn;
    }
}

extern "C" void kernel_launch(void* const* d_in, const int* in_sizes, int n_in,
                              void* d_out, int out_size, void* d_ws, size_t ws_size,
                              hipStream_t stream) {
    const float* x         = (const float*)d_in[0];
    const float* w1        = (const float*)d_in[1];
    const float* b1        = (const float*)d_in[2];
    const float* fscale    = (const float*)d_in[3];
    const float* conv_bias = (const float*)d_in[4];
    float* out = (float*)d_out;

    float* avg = (float*)d_ws;        // 1024 floats
    float* wk  = avg + NP;            // 9216 floats

    mean_kernel<<<NP, 256, 0, stream>>>(x, avg);
    wk_kernel<<<(BB * CC * 9 + 255) / 256, 256, 0, stream>>>(avg, w1, b1, wk);
    conv_kernel<<<NP, 256, 0, stream>>>(x, wk, fscale, conv_bias, out);
}